// Round 1
// baseline (426.534 us; speedup 1.0000x reference)
//
#include <hip/hip_runtime.h>
#include <hip/hip_bf16.h>

#define BB 4
#define NN 4096
#define FF 128
#define UU 64

typedef float  f32x4   __attribute__((ext_vector_type(4)));
typedef __bf16 bf16x8  __attribute__((ext_vector_type(8)));
typedef int    int4v   __attribute__((ext_vector_type(4)));
typedef float  flt4v   __attribute__((ext_vector_type(4)));
typedef unsigned short us4 __attribute__((ext_vector_type(4)));

__device__ __forceinline__ unsigned short f2bf(float x) {
    unsigned u = __float_as_uint(x);
    u += 0x7FFFu + ((u >> 16) & 1u);   // round-to-nearest-even
    return (unsigned short)(u >> 16);
}

// Kernel 1: Wh = h @ W (fp32), src/dst = Wh·a1 / Wh·a2, store WhT bf16 [b][u][j]
__global__ __launch_bounds__(256) void prep_kernel(
    const float* __restrict__ h, const float* __restrict__ W,
    const float* __restrict__ a,
    unsigned short* __restrict__ WhT, float* __restrict__ src, float* __restrict__ dst)
{
    __shared__ float Wl[FF][UU];             // 32 KB
    __shared__ unsigned short tile[16][UU];  // 2 KB
    const int t = threadIdx.x, w = t >> 6, l = t & 63;
    const int bid = blockIdx.x;
    const int b = bid >> 8;                  // N/16 = 256 blocks per batch
    const int i0 = (bid & 255) << 4;

    // stage W into LDS (8192 floats, 32 per thread)
    {
        const flt4v* Wv = (const flt4v*)W;
        flt4v* Wlv = (flt4v*)&Wl[0][0];
        #pragma unroll
        for (int k = 0; k < 8; ++k) Wlv[t + 256 * k] = Wv[t + 256 * k];
    }
    __syncthreads();

    // wave w computes rows i0 + 4w .. i0 + 4w+3 ; lane = u
    float acc[4] = {0.f, 0.f, 0.f, 0.f};
    const float* hrow = h + ((size_t)(b * NN + i0 + w * 4) * FF);
    #pragma unroll 4
    for (int f = 0; f < FF; ++f) {
        float wv = Wl[f][l];
        acc[0] += hrow[f] * wv;
        acc[1] += hrow[FF + f] * wv;
        acc[2] += hrow[2 * FF + f] * wv;
        acc[3] += hrow[3 * FF + f] * wv;
    }

    float a1 = a[l], a2 = a[UU + l];
    #pragma unroll
    for (int k = 0; k < 4; ++k) {
        float s = acc[k] * a1, d = acc[k] * a2;
        #pragma unroll
        for (int off = 32; off > 0; off >>= 1) {
            s += __shfl_xor(s, off, 64);
            d += __shfl_xor(d, off, 64);
        }
        int i = i0 + w * 4 + k;
        if (l == 0) { src[b * NN + i] = s; dst[b * NN + i] = d; }
        tile[w * 4 + k][l] = f2bf(acc[k]);
    }
    __syncthreads();

    // transposed, coalesced-ish store: thread t -> u = t>>2, 4 consecutive i
    {
        int u = t >> 2, ic = (t & 3) << 2;
        us4 vv = { tile[ic + 0][u], tile[ic + 1][u], tile[ic + 2][u], tile[ic + 3][u] };
        *(us4*)(WhT + ((size_t)(b * UU + u) * NN) + i0 + ic) = vv;
    }
}

// Kernel 2: flash-style rank-1-score attention + BN + ReLU
__global__ __launch_bounds__(256) void gat_kernel(
    const int* __restrict__ adj, const unsigned short* __restrict__ WhT,
    const float* __restrict__ src, const float* __restrict__ dst,
    const float* __restrict__ gamma, const float* __restrict__ beta,
    const float* __restrict__ mmean, const float* __restrict__ mvar,
    float* __restrict__ out)
{
    __shared__ float opart[4][16][UU];  // 16 KB
    __shared__ float lpart[4][16];
    const int t = threadIdx.x, w = t >> 6, l = t & 63;
    const int bid = blockIdx.x;
    const int b = bid >> 8;
    const int i0 = (bid & 255) << 4;
    const int row = l & 15;     // A-frag row (= i within tile) and B-frag n (= u low)
    const int kg = l >> 4;      // k-chunk group 0..3
    const int i = i0 + row;

    const float srow = src[b * NN + i];
    const int* adjr = adj + ((size_t)(b * NN + i) << 12);
    const float* dstb = dst + b * NN;
    const unsigned short* w0 = WhT + ((size_t)(b * UU + row) * NN);

    f32x4 acc0 = {0,0,0,0}, acc1 = {0,0,0,0}, acc2 = {0,0,0,0}, acc3 = {0,0,0,0};
    float lsum = 0.f;

    auto compute = [&](int4v A0, int4v A1, flt4v D0, flt4v D1,
                       bf16x8 Bv0, bf16x8 Bv1, bf16x8 Bv2, bf16x8 Bv3) {
        bf16x8 af;
        #define PE(e, Dv, Av, ei)                                   \
        {                                                           \
            float tt = srow + Dv[ei];                               \
            tt = fmaxf(tt, 0.2f * tt);      /* LeakyReLU */         \
            float pp = __expf(tt);                                  \
            pp = (Av[ei] > 0) ? pp : 0.0f;  /* adjacency mask */    \
            lsum += pp;                                             \
            af[e] = (__bf16)pp;                                     \
        }
        PE(0, D0, A0, 0) PE(1, D0, A0, 1) PE(2, D0, A0, 2) PE(3, D0, A0, 3)
        PE(4, D1, A1, 0) PE(5, D1, A1, 1) PE(6, D1, A1, 2) PE(7, D1, A1, 3)
        #undef PE
        acc0 = __builtin_amdgcn_mfma_f32_16x16x32_bf16(af, Bv0, acc0, 0, 0, 0);
        acc1 = __builtin_amdgcn_mfma_f32_16x16x32_bf16(af, Bv1, acc1, 0, 0, 0);
        acc2 = __builtin_amdgcn_mfma_f32_16x16x32_bf16(af, Bv2, acc2, 0, 0, 0);
        acc3 = __builtin_amdgcn_mfma_f32_16x16x32_bf16(af, Bv3, acc3, 0, 0, 0);
    };

    // wave w handles j-chunks c = w, w+4, ... (chunk = 32 columns); 32 chunks/wave
    int jl = (w << 5) + (kg << 3);
    int4v  A0 = *(const int4v*)(adjr + jl);
    int4v  A1 = *(const int4v*)(adjr + jl + 4);
    flt4v  D0 = *(const flt4v*)(dstb + jl);
    flt4v  D1 = *(const flt4v*)(dstb + jl + 4);
    bf16x8 B0 = *(const bf16x8*)(w0 + jl);
    bf16x8 B1 = *(const bf16x8*)(w0 + 16 * NN + jl);
    bf16x8 B2 = *(const bf16x8*)(w0 + 32 * NN + jl);
    bf16x8 B3 = *(const bf16x8*)(w0 + 48 * NN + jl);

    for (int it = 0; it < 31; ++it) {
        const int jn = jl + 128;  // next chunk for this wave (c += 4)
        int4v  nA0 = *(const int4v*)(adjr + jn);
        int4v  nA1 = *(const int4v*)(adjr + jn + 4);
        flt4v  nD0 = *(const flt4v*)(dstb + jn);
        flt4v  nD1 = *(const flt4v*)(dstb + jn + 4);
        bf16x8 nB0 = *(const bf16x8*)(w0 + jn);
        bf16x8 nB1 = *(const bf16x8*)(w0 + 16 * NN + jn);
        bf16x8 nB2 = *(const bf16x8*)(w0 + 32 * NN + jn);
        bf16x8 nB3 = *(const bf16x8*)(w0 + 48 * NN + jn);
        compute(A0, A1, D0, D1, B0, B1, B2, B3);
        A0 = nA0; A1 = nA1; D0 = nD0; D1 = nD1;
        B0 = nB0; B1 = nB1; B2 = nB2; B3 = nB3;
        jl = jn;
    }
    compute(A0, A1, D0, D1, B0, B1, B2, B3);

    // row-sum partials: lanes {r, r+16, r+32, r+48} hold row r
    lsum += __shfl_xor(lsum, 16, 64);
    lsum += __shfl_xor(lsum, 32, 64);
    if (l < 16) lpart[w][l] = lsum;

    // C layout: col = l&15 (u low), row = kg*4 + reg
    #pragma unroll
    for (int r = 0; r < 4; ++r) {
        opart[w][kg * 4 + r][      row] = acc0[r];
        opart[w][kg * 4 + r][16 + row] = acc1[r];
        opart[w][kg * 4 + r][32 + row] = acc2[r];
        opart[w][kg * 4 + r][48 + row] = acc3[r];
    }
    __syncthreads();

    // combine 4 wave-partials, normalize, BN + ReLU, coalesced store
    const int u = t & 63;
    const float inv = rsqrtf(mvar[u] + 1e-3f);
    const float sc = gamma[u] * inv;
    const float bi = beta[u] - mmean[u] * sc;
    const int ib = (t >> 6) << 2;
    #pragma unroll
    for (int r = 0; r < 4; ++r) {
        int il = ib + r;
        float ltot = lpart[0][il] + lpart[1][il] + lpart[2][il] + lpart[3][il];
        float v = opart[0][il][u] + opart[1][il][u] + opart[2][il][u] + opart[3][il][u];
        v = v / ltot * sc + bi;
        out[((size_t)(b * NN + i0 + il) << 6) + u] = fmaxf(v, 0.f);
    }
}

extern "C" void kernel_launch(void* const* d_in, const int* in_sizes, int n_in,
                              void* d_out, int out_size, void* d_ws, size_t ws_size,
                              hipStream_t stream) {
    const float* h     = (const float*)d_in[0];
    const int*   adj   = (const int*)  d_in[1];
    const float* W     = (const float*)d_in[2];
    const float* a     = (const float*)d_in[3];
    const float* gamma = (const float*)d_in[4];
    const float* beta  = (const float*)d_in[5];
    const float* mmean = (const float*)d_in[6];
    const float* mvar  = (const float*)d_in[7];
    float* out = (float*)d_out;

    unsigned short* WhT = (unsigned short*)d_ws;                       // 2 MiB
    float* src = (float*)((char*)d_ws + (size_t)2 * 1024 * 1024);      // 64 KB
    float* dst = src + BB * NN;                                        // 64 KB

    prep_kernel<<<BB * (NN / 16), 256, 0, stream>>>(h, W, a, WhT, src, dst);
    gat_kernel<<<BB * (NN / 16), 256, 0, stream>>>(adj, WhT, src, dst,
                                                   gamma, beta, mmean, mvar, out);
}

// Round 2
// 417.732 us; speedup vs baseline: 1.0211x; 1.0211x over previous
//
#include <hip/hip_runtime.h>
#include <hip/hip_bf16.h>

#define BB 4
#define NN 4096
#define FF 128
#define UU 64
#define LOG2E 1.4426950408889634f

typedef float  f32x4   __attribute__((ext_vector_type(4)));
typedef __bf16 bf16x8  __attribute__((ext_vector_type(8)));
typedef int    int4v   __attribute__((ext_vector_type(4)));
typedef float  flt4v   __attribute__((ext_vector_type(4)));
typedef unsigned short us4 __attribute__((ext_vector_type(4)));

__device__ __forceinline__ unsigned short f2bf(float x) {
    unsigned u = __float_as_uint(x);
    u += 0x7FFFu + ((u >> 16) & 1u);   // round-to-nearest-even
    return (unsigned short)(u >> 16);
}

__device__ __forceinline__ float fexp2(float x) {
#if defined(__has_builtin)
# if __has_builtin(__builtin_amdgcn_exp2f)
    return __builtin_amdgcn_exp2f(x);
# else
    return exp2f(x);
# endif
#else
    return exp2f(x);
#endif
}

// Kernel 1: Wh = h @ W (fp32), src/dst = (Wh·a)/ln2, WhT bf16 [b][u][j]
__global__ __launch_bounds__(256) void prep_kernel(
    const float* __restrict__ h, const float* __restrict__ W,
    const float* __restrict__ a,
    unsigned short* __restrict__ WhT, float* __restrict__ src, float* __restrict__ dst)
{
    __shared__ float Wl[FF][UU];             // 32 KB
    __shared__ unsigned short tile[16][UU];  // 2 KB
    const int t = threadIdx.x, w = t >> 6, l = t & 63;
    const int bid = blockIdx.x;
    const int b = bid >> 8;                  // N/16 = 256 blocks per batch
    const int i0 = (bid & 255) << 4;

    // stage W into LDS (8192 floats, 32 per thread)
    {
        const flt4v* Wv = (const flt4v*)W;
        flt4v* Wlv = (flt4v*)&Wl[0][0];
        #pragma unroll
        for (int k = 0; k < 8; ++k) Wlv[t + 256 * k] = Wv[t + 256 * k];
    }
    __syncthreads();

    // wave w computes rows i0 + 4w .. i0 + 4w+3 ; lane = u
    float acc[4] = {0.f, 0.f, 0.f, 0.f};
    const float* hrow = h + ((size_t)(b * NN + i0 + w * 4) * FF);
    #pragma unroll 4
    for (int f = 0; f < FF; ++f) {
        float wv = Wl[f][l];
        acc[0] += hrow[f] * wv;
        acc[1] += hrow[FF + f] * wv;
        acc[2] += hrow[2 * FF + f] * wv;
        acc[3] += hrow[3 * FF + f] * wv;
    }

    float a1 = a[l], a2 = a[UU + l];
    #pragma unroll
    for (int k = 0; k < 4; ++k) {
        float s = acc[k] * a1, d = acc[k] * a2;
        #pragma unroll
        for (int off = 32; off > 0; off >>= 1) {
            s += __shfl_xor(s, off, 64);
            d += __shfl_xor(d, off, 64);
        }
        int i = i0 + w * 4 + k;
        if (l == 0) {
            src[b * NN + i] = s * LOG2E;   // fold 1/ln2 -> use exp2 downstream
            dst[b * NN + i] = d * LOG2E;
        }
        tile[w * 4 + k][l] = f2bf(acc[k]);
    }
    __syncthreads();

    // transposed store: thread t -> u = t>>2, 4 consecutive i
    {
        int u = t >> 2, ic = (t & 3) << 2;
        us4 vv = { tile[ic + 0][u], tile[ic + 1][u], tile[ic + 2][u], tile[ic + 3][u] };
        *(us4*)(WhT + ((size_t)(b * UU + u) * NN) + i0 + ic) = vv;
    }
}

#define MFMA16(A, B, C) __builtin_amdgcn_mfma_f32_16x16x32_bf16(A, B, C, 0, 0, 0)

// Kernel 2: flash-style rank-1-score attention + BN + ReLU
// 4 waves share 16 rows, stripe j; 64 j per wave per iteration; adj (HBM)
// software-pipelined 1 chunk ahead; dst/WhT (L2-resident) loaded in-iteration.
__global__ __launch_bounds__(256, 4) void gat_kernel(
    const int* __restrict__ adj, const unsigned short* __restrict__ WhT,
    const float* __restrict__ src, const float* __restrict__ dst,
    const float* __restrict__ gamma, const float* __restrict__ beta,
    const float* __restrict__ mmean, const float* __restrict__ mvar,
    float* __restrict__ out)
{
    __shared__ float opart[4][16][UU];  // 16 KB
    __shared__ float lpart[4][16];
    const int t = threadIdx.x, w = t >> 6, l = t & 63;
    const int bid = blockIdx.x;
    const int b = bid >> 8;
    const int i0 = (bid & 255) << 4;
    const int row = l & 15;     // A-frag row (i within tile) == B-frag col (u low)
    const int kg = l >> 4;      // k-group 0..3
    const int ko = kg << 3;
    const int i = i0 + row;

    const float srow = src[b * NN + i];
    const int* adjr = adj + ((size_t)(b * NN + i) << 12);
    const float* dstb = dst + b * NN;
    const unsigned short* w0 = WhT + ((size_t)(b * UU + row) * NN);

    f32x4 acc0 = {0,0,0,0}, acc1 = {0,0,0,0}, acc2 = {0,0,0,0}, acc3 = {0,0,0,0};
    float ls0 = 0.f, ls1 = 0.f;

    // softmax-numerators for 8 j's -> bf16 A-fragment
    #define PE(af, e, Dv, Av, ei, ls)                               \
    {                                                               \
        float tt = srow + Dv[ei];                                   \
        tt = fmaxf(tt, 0.2f * tt);      /* LeakyReLU (log2 units) */\
        float pp = fexp2(tt);                                       \
        pp = (Av[ei] > 0) ? pp : 0.0f;  /* adjacency mask */        \
        ls += pp;                                                   \
        af[e] = (__bf16)pp;                                         \
    }

    int4v cA0a, cA0b, cA1a, cA1b;   // current iteration's adj (64 j / wave)
    int base = w << 6;
    cA0a = *(const int4v*)(adjr + base + ko);
    cA0b = *(const int4v*)(adjr + base + ko + 4);
    cA1a = *(const int4v*)(adjr + base + ko + 32);
    cA1b = *(const int4v*)(adjr + base + ko + 36);

    auto body = [&](int bs, int4v A0a, int4v A0b, int4v A1a, int4v A1b) {
        // --- k-half 0: j = bs+ko .. bs+ko+7 ---
        const flt4v  D0a = *(const flt4v*)(dstb + bs + ko);
        const flt4v  D0b = *(const flt4v*)(dstb + bs + ko + 4);
        const bf16x8 B00 = *(const bf16x8*)(w0 + bs + ko);
        const bf16x8 B01 = *(const bf16x8*)(w0 + 16 * NN + bs + ko);
        const bf16x8 B02 = *(const bf16x8*)(w0 + 32 * NN + bs + ko);
        const bf16x8 B03 = *(const bf16x8*)(w0 + 48 * NN + bs + ko);
        bf16x8 af0;
        PE(af0, 0, D0a, A0a, 0, ls0) PE(af0, 1, D0a, A0a, 1, ls0)
        PE(af0, 2, D0a, A0a, 2, ls0) PE(af0, 3, D0a, A0a, 3, ls0)
        PE(af0, 4, D0b, A0b, 0, ls0) PE(af0, 5, D0b, A0b, 1, ls0)
        PE(af0, 6, D0b, A0b, 2, ls0) PE(af0, 7, D0b, A0b, 3, ls0)
        acc0 = MFMA16(af0, B00, acc0);
        acc1 = MFMA16(af0, B01, acc1);
        acc2 = MFMA16(af0, B02, acc2);
        acc3 = MFMA16(af0, B03, acc3);
        // --- k-half 1: j = bs+32+ko .. ---
        const flt4v  D1a = *(const flt4v*)(dstb + bs + ko + 32);
        const flt4v  D1b = *(const flt4v*)(dstb + bs + ko + 36);
        const bf16x8 B10 = *(const bf16x8*)(w0 + bs + ko + 32);
        const bf16x8 B11 = *(const bf16x8*)(w0 + 16 * NN + bs + ko + 32);
        const bf16x8 B12 = *(const bf16x8*)(w0 + 32 * NN + bs + ko + 32);
        const bf16x8 B13 = *(const bf16x8*)(w0 + 48 * NN + bs + ko + 32);
        bf16x8 af1;
        PE(af1, 0, D1a, A1a, 0, ls1) PE(af1, 1, D1a, A1a, 1, ls1)
        PE(af1, 2, D1a, A1a, 2, ls1) PE(af1, 3, D1a, A1a, 3, ls1)
        PE(af1, 4, D1b, A1b, 0, ls1) PE(af1, 5, D1b, A1b, 1, ls1)
        PE(af1, 6, D1b, A1b, 2, ls1) PE(af1, 7, D1b, A1b, 3, ls1)
        acc0 = MFMA16(af1, B10, acc0);
        acc1 = MFMA16(af1, B11, acc1);
        acc2 = MFMA16(af1, B12, acc2);
        acc3 = MFMA16(af1, B13, acc3);
    };

    for (int it = 0; it < 15; ++it) {
        const int nb = base + 256;  // next chunk for this wave
        int4v nA0a = *(const int4v*)(adjr + nb + ko);
        int4v nA0b = *(const int4v*)(adjr + nb + ko + 4);
        int4v nA1a = *(const int4v*)(adjr + nb + ko + 32);
        int4v nA1b = *(const int4v*)(adjr + nb + ko + 36);
        body(base, cA0a, cA0b, cA1a, cA1b);
        cA0a = nA0a; cA0b = nA0b; cA1a = nA1a; cA1b = nA1b;
        base = nb;
    }
    body(base, cA0a, cA0b, cA1a, cA1b);
    #undef PE

    // row-sum partials: lanes {r, r+16, r+32, r+48} hold row r
    float lsum = ls0 + ls1;
    lsum += __shfl_xor(lsum, 16, 64);
    lsum += __shfl_xor(lsum, 32, 64);
    if (l < 16) lpart[w][l] = lsum;

    // C layout: col = l&15 (u low), row(m) = kg*4 + reg
    #pragma unroll
    for (int r = 0; r < 4; ++r) {
        opart[w][kg * 4 + r][      row] = acc0[r];
        opart[w][kg * 4 + r][16 + row] = acc1[r];
        opart[w][kg * 4 + r][32 + row] = acc2[r];
        opart[w][kg * 4 + r][48 + row] = acc3[r];
    }
    __syncthreads();

    // combine 4 wave-partials, normalize, BN + ReLU, coalesced store
    const int u = t & 63;
    const float inv = rsqrtf(mvar[u] + 1e-3f);
    const float sc = gamma[u] * inv;
    const float bi = beta[u] - mmean[u] * sc;
    const int ib = (t >> 6) << 2;
    #pragma unroll
    for (int r = 0; r < 4; ++r) {
        int il = ib + r;
        float ltot = lpart[0][il] + lpart[1][il] + lpart[2][il] + lpart[3][il];
        float v = opart[0][il][u] + opart[1][il][u] + opart[2][il][u] + opart[3][il][u];
        v = v / ltot * sc + bi;
        out[((size_t)(b * NN + i0 + il) << 6) + u] = fmaxf(v, 0.f);
    }
}

extern "C" void kernel_launch(void* const* d_in, const int* in_sizes, int n_in,
                              void* d_out, int out_size, void* d_ws, size_t ws_size,
                              hipStream_t stream) {
    const float* h     = (const float*)d_in[0];
    const int*   adj   = (const int*)  d_in[1];
    const float* W     = (const float*)d_in[2];
    const float* a     = (const float*)d_in[3];
    const float* gamma = (const float*)d_in[4];
    const float* beta  = (const float*)d_in[5];
    const float* mmean = (const float*)d_in[6];
    const float* mvar  = (const float*)d_in[7];
    float* out = (float*)d_out;

    unsigned short* WhT = (unsigned short*)d_ws;                       // 2 MiB
    float* src = (float*)((char*)d_ws + (size_t)2 * 1024 * 1024);      // 64 KB
    float* dst = src + BB * NN;                                        // 64 KB

    prep_kernel<<<BB * (NN / 16), 256, 0, stream>>>(h, W, a, WhT, src, dst);
    gat_kernel<<<BB * (NN / 16), 256, 0, stream>>>(adj, WhT, src, dst,
                                                   gamma, beta, mmean, mvar, out);
}